// Round 15
// baseline (197.732 us; speedup 1.0000x reference)
//
#include <hip/hip_runtime.h>

#define N_TOK 2048
#define IN_FEAT 2048
#define NNZB 1228
#define XN8 ((N_TOK * IN_FEAT) / 8)   // x elements / 8
#define WN8 ((NNZB * 1024) / 8)       // w elements / 8

typedef __attribute__((ext_vector_type(8))) short short8;
typedef __attribute__((ext_vector_type(4))) float floatx4;

__device__ __forceinline__ short f2bf(float f) {
  unsigned u = __builtin_bit_cast(unsigned, f);
  u += 0x7FFFu + ((u >> 16) & 1u);   // round-to-nearest-even
  return (short)(u >> 16);
}

__device__ __forceinline__ short8 cvt8(const float4 a, const float4 b) {
  short8 r;
  r[0] = f2bf(a.x); r[1] = f2bf(a.y); r[2] = f2bf(a.z); r[3] = f2bf(a.w);
  r[4] = f2bf(b.x); r[5] = f2bf(b.y); r[6] = f2bf(b.z); r[7] = f2bf(b.w);
  return r;
}

// One-shot f32 -> bf16 conversion of x and w into workspace; block 0 also
// precomputes per-output-block nnz range offsets (oi is sorted).
__global__ __launch_bounds__(256) void cvt_kernel(
    const float* __restrict__ x, const float* __restrict__ w,
    const int* __restrict__ oi,
    short8* __restrict__ xb, short8* __restrict__ wb, int* __restrict__ offs) {
  const int tid = blockIdx.x * 256 + threadIdx.x;
  if (blockIdx.x == 0 && threadIdx.x < 65) {
    const int target = threadIdx.x;
    int lo = 0, hi = NNZB;
    while (lo < hi) { int m = (lo + hi) >> 1; if (oi[m] < target) lo = m + 1; else hi = m; }
    offs[threadIdx.x] = lo;
  }
  if (tid < XN8) {
    const float4* p = (const float4*)x + (size_t)tid * 2;
    xb[tid] = cvt8(p[0], p[1]);
  } else if (tid < XN8 + WN8) {
    const int t = tid - XN8;
    const float4* p = (const float4*)w + (size_t)t * 2;
    wb[t] = cvt8(p[0], p[1]);
  }
}

// INSTRUMENTATION BUILD: K-loop executed `passes` times (runtime arg, host
// passes 5) accumulating 5x into acc; final write scales by 1/passes.
// Identical numerics; ~5x k-loop duration so (a) bsl_main rises above the
// harness's 44-us d_ws poison fills into the rocprof top-5, and (b)
// (T(5) - T(1))/4 vs R10's 105.6 us gives the pure k-loop marginal cost.
template <int USE_WS>
__global__ __launch_bounds__(256, 4) void bsl_main(
    const short8* __restrict__ xb, const short8* __restrict__ wb,
    const int* __restrict__ offs,
    const float* __restrict__ x, const float* __restrict__ w,
    const int* __restrict__ oi, const int* __restrict__ ii,
    float* __restrict__ y, int passes) {
  const int ob   = blockIdx.x >> 5;
  const int tile = blockIdx.x & 31;
  const int lane = threadIdx.x & 63;
  const int wv   = __builtin_amdgcn_readfirstlane(threadIdx.x >> 6);
  const int row16 = lane & 15;
  const int kgrp  = lane >> 4;   // 0..3

  __shared__ float red[2][64 * 32];

  int e0, e1;
  if (USE_WS) {
    e0 = offs[ob];
    e1 = offs[ob + 1];
  } else {
    int lo = 0, hi = NNZB;
    while (lo < hi) { int m = (lo + hi) >> 1; if (oi[m] < ob) lo = m + 1; else hi = m; }
    e0 = lo;
    hi = NNZB;
    while (lo < hi) { int m = (lo + hi) >> 1; if (oi[m] < ob + 1) lo = m + 1; else hi = m; }
    e1 = lo;
  }
  const int cnt = e1 - e0;
  const int ks = e0 + (cnt * wv) / 4;
  const int ke = e0 + (cnt * (wv + 1)) / 4;

  const int tokBase = tile * 64;

  floatx4 acc[4][2] = {};
  const float inv_passes = 1.0f / (float)passes;

  #pragma unroll 1
  for (int pass = 0; pass < passes; ++pass) {
    if (USE_WS) {
      const short8* xrow = xb + (size_t)(tokBase + row16) * 256 + kgrp;
      #pragma unroll 2
      for (int k = ks; k < ke; ++k) {
        const int ib = ii[k];
        short8 b0 = wb[(size_t)k * 128 + row16 * 4 + kgrp];
        short8 b1 = wb[(size_t)k * 128 + (row16 + 16) * 4 + kgrp];
        const short8* xp = xrow + ib * 4;
        #pragma unroll
        for (int m = 0; m < 4; ++m) {
          short8 a = xp[m * 16 * 256];
          acc[m][0] = __builtin_amdgcn_mfma_f32_16x16x32_bf16(a, b0, acc[m][0], 0, 0, 0);
          acc[m][1] = __builtin_amdgcn_mfma_f32_16x16x32_bf16(a, b1, acc[m][1], 0, 0, 0);
        }
      }
    } else {
      const float* xrow = x + (size_t)(tokBase + row16) * IN_FEAT + kgrp * 8;
      #pragma unroll 2
      for (int k = ks; k < ke; ++k) {
        const int ib = ii[k];
        const float* wbp = w + (size_t)k * 1024 + kgrp * 8;
        const float4* wp0 = (const float4*)(wbp + row16 * 32);
        const float4* wp1 = (const float4*)(wbp + (row16 + 16) * 32);
        short8 b0 = cvt8(wp0[0], wp0[1]);
        short8 b1 = cvt8(wp1[0], wp1[1]);
        const float* xp = xrow + ib * 32;
        #pragma unroll
        for (int m = 0; m < 4; ++m) {
          const float4* ap = (const float4*)(xp + (size_t)(m * 16) * IN_FEAT);
          short8 a = cvt8(ap[0], ap[1]);
          acc[m][0] = __builtin_amdgcn_mfma_f32_16x16x32_bf16(a, b0, acc[m][0], 0, 0, 0);
          acc[m][1] = __builtin_amdgcn_mfma_f32_16x16x32_bf16(a, b1, acc[m][1], 0, 0, 0);
        }
      }
    }
  }

  // tree reduce: (1->0, 3->2) then (2->0); wave 0 writes out (scaled 1/passes).
  {
    float* b0p = red[0];
    float* b1p = red[1];
    if (wv == 1 || wv == 3) {
      float* b = (wv == 1) ? b0p : b1p;
      #pragma unroll
      for (int m = 0; m < 4; ++m)
        #pragma unroll
        for (int nf = 0; nf < 2; ++nf)
          #pragma unroll
          for (int r = 0; r < 4; ++r)
            b[(m * 16 + kgrp * 4 + r) * 32 + nf * 16 + row16] = acc[m][nf][r];
    }
    __syncthreads();
    if (wv == 0 || wv == 2) {
      const float* b = (wv == 0) ? b0p : b1p;
      #pragma unroll
      for (int m = 0; m < 4; ++m)
        #pragma unroll
        for (int nf = 0; nf < 2; ++nf)
          #pragma unroll
          for (int r = 0; r < 4; ++r)
            acc[m][nf][r] += b[(m * 16 + kgrp * 4 + r) * 32 + nf * 16 + row16];
    }
    __syncthreads();
    if (wv == 2) {
      #pragma unroll
      for (int m = 0; m < 4; ++m)
        #pragma unroll
        for (int nf = 0; nf < 2; ++nf)
          #pragma unroll
          for (int r = 0; r < 4; ++r)
            b0p[(m * 16 + kgrp * 4 + r) * 32 + nf * 16 + row16] = acc[m][nf][r];
    }
    __syncthreads();
    if (wv == 0) {
      #pragma unroll
      for (int m = 0; m < 4; ++m)
        #pragma unroll
        for (int nf = 0; nf < 2; ++nf)
          #pragma unroll
          for (int r = 0; r < 4; ++r) {
            float v = (acc[m][nf][r] + b0p[(m * 16 + kgrp * 4 + r) * 32 + nf * 16 + row16]) * inv_passes;
            const int row = tokBase + m * 16 + kgrp * 4 + r;
            const int col = ob * 32 + nf * 16 + row16;
            y[(size_t)row * 2048 + col] = v;
          }
    }
  }
}

extern "C" void kernel_launch(void* const* d_in, const int* in_sizes, int n_in,
                              void* d_out, int out_size, void* d_ws, size_t ws_size,
                              hipStream_t stream) {
  const float* x  = (const float*)d_in[0];
  const float* w  = (const float*)d_in[1];
  const int*   oi = (const int*)d_in[2];
  const int*   ii = (const int*)d_in[3];
  float* y = (float*)d_out;

  const size_t need = (size_t)(XN8 + WN8) * 16 + 65 * sizeof(int);
  if (ws_size >= need) {
    short8* xb = (short8*)d_ws;
    short8* wb = xb + XN8;
    int* offs = (int*)(wb + WN8);
    cvt_kernel<<<dim3((XN8 + WN8 + 255) / 256), dim3(256), 0, stream>>>(x, w, oi, xb, wb, offs);
    bsl_main<1><<<dim3(2048), dim3(256), 0, stream>>>(xb, wb, offs, x, w, oi, ii, y, 5);
  } else {
    bsl_main<0><<<dim3(2048), dim3(256), 0, stream>>>(nullptr, nullptr, nullptr, x, w, oi, ii, y, 5);
  }
}

// Round 17
// 105.796 us; speedup vs baseline: 1.8690x; 1.8690x over previous
//
#include <hip/hip_runtime.h>

#define N_TOK 2048
#define IN_FEAT 2048
#define NNZB 1228
#define XN8 ((N_TOK * IN_FEAT) / 8)   // x elements / 8
#define WN8 ((NNZB * 1024) / 8)       // w elements / 8

typedef __attribute__((ext_vector_type(8))) short short8;
typedef __attribute__((ext_vector_type(4))) float floatx4;

__device__ __forceinline__ short f2bf(float f) {
  unsigned u = __builtin_bit_cast(unsigned, f);
  u += 0x7FFFu + ((u >> 16) & 1u);   // round-to-nearest-even
  return (short)(u >> 16);
}

__device__ __forceinline__ short8 cvt8(const float4 a, const float4 b) {
  short8 r;
  r[0] = f2bf(a.x); r[1] = f2bf(a.y); r[2] = f2bf(a.z); r[3] = f2bf(a.w);
  r[4] = f2bf(b.x); r[5] = f2bf(b.y); r[6] = f2bf(b.z); r[7] = f2bf(b.w);
  return r;
}

// One-shot f32 -> bf16 conversion of x and w into workspace; block 0 also
// precomputes per-output-block nnz range offsets (oi is sorted).
__global__ __launch_bounds__(256) void cvt_kernel(
    const float* __restrict__ x, const float* __restrict__ w,
    const int* __restrict__ oi,
    short8* __restrict__ xb, short8* __restrict__ wb, int* __restrict__ offs) {
  const int tid = blockIdx.x * 256 + threadIdx.x;
  if (blockIdx.x == 0 && threadIdx.x < 65) {
    const int target = threadIdx.x;
    int lo = 0, hi = NNZB;
    while (lo < hi) { int m = (lo + hi) >> 1; if (oi[m] < target) lo = m + 1; else hi = m; }
    offs[threadIdx.x] = lo;
  }
  if (tid < XN8) {
    const float4* p = (const float4*)x + (size_t)tid * 2;
    xb[tid] = cvt8(p[0], p[1]);
  } else if (tid < XN8 + WN8) {
    const int t = tid - XN8;
    const float4* p = (const float4*)w + (size_t)t * 2;
    wb[t] = cvt8(p[0], p[1]);
  }
}

// R15 diagnosis: all counters low at 58% occupancy, warm L2, ~13k cy per
// k-iteration => cross-wave same-address serialization + index-load chain.
// This build: (1) ii[] preloaded into lanes, ib via v_readlane (no mem op in
// the index path); (2) k-order staggered across tiles/waves to decorrelate
// same-line storms; (3) manual 2-deep software pipeline (named A/B regs).
template <int USE_WS>
__global__ __launch_bounds__(256, 4) void bsl_main(
    const short8* __restrict__ xb, const short8* __restrict__ wb,
    const int* __restrict__ offs,
    const float* __restrict__ x, const float* __restrict__ w,
    const int* __restrict__ oi, const int* __restrict__ ii,
    float* __restrict__ y) {
  const int ob   = blockIdx.x >> 5;
  const int tile = blockIdx.x & 31;
  const int lane = threadIdx.x & 63;
  const int wv   = __builtin_amdgcn_readfirstlane(threadIdx.x >> 6);
  const int row16 = lane & 15;
  const int kgrp  = lane >> 4;   // 0..3

  __shared__ float red[2][64 * 32];

  int e0, e1;
  if (USE_WS) {
    e0 = offs[ob];
    e1 = offs[ob + 1];
  } else {
    int lo = 0, hi = NNZB;
    while (lo < hi) { int m = (lo + hi) >> 1; if (oi[m] < ob) lo = m + 1; else hi = m; }
    e0 = lo;
    hi = NNZB;
    while (lo < hi) { int m = (lo + hi) >> 1; if (oi[m] < ob + 1) lo = m + 1; else hi = m; }
    e1 = lo;
  }
  const int cnt = e1 - e0;

  // preload up to 64 block indices into the wave's lanes (one load total)
  const int safek = (lane < cnt) ? (e0 + lane) : 0;
  const int iiv = ii[safek];

  // wave slice, rotated per tile so concurrent tiles read different k
  const int q   = (wv + tile) & 3;
  const int js  = (cnt * q) >> 2;
  const int je  = (cnt * (q + 1)) >> 2;
  const int len = je - js;
  const int rot = (len > 0) ? ((((tile >> 2) & 7) * len) >> 3) : 0;

  const int tokBase = tile * 64;

  floatx4 acc[4][2] = {};

  if (len > 0) {
    const short8* xrow = xb + (size_t)(tokBase + row16) * 256 + kgrp;

    short8 b0A, b1A, a0A, a1A, a2A, a3A;
    short8 b0B, b1B, a0B, a1B, a2B, a3B;

#define JJ(r_) ({ int rr_ = (r_) + rot; if (rr_ >= len) rr_ -= len; js + rr_; })

#define LD(j_, b0_, b1_, a0_, a1_, a2_, a3_)                                   \
  {                                                                            \
    const int j__ = (j_);                                                      \
    const int k__ = e0 + j__;                                                  \
    const int ib__ = (j__ < 64) ? __builtin_amdgcn_readlane(iiv, j__)          \
                                : ii[k__];                                     \
    const short8* wp__ = wb + (size_t)k__ * 128 + row16 * 4 + kgrp;            \
    b0_ = wp__[0];                                                             \
    b1_ = wp__[64];                                                            \
    const short8* xp__ = xrow + ib__ * 4;                                      \
    a0_ = xp__[0];                                                             \
    a1_ = xp__[16 * 256];                                                      \
    a2_ = xp__[32 * 256];                                                      \
    a3_ = xp__[48 * 256];                                                      \
  }

#define FMA(b0_, b1_, a0_, a1_, a2_, a3_)                                      \
  {                                                                            \
    acc[0][0] = __builtin_amdgcn_mfma_f32_16x16x32_bf16(a0_, b0_, acc[0][0], 0, 0, 0); \
    acc[0][1] = __builtin_amdgcn_mfma_f32_16x16x32_bf16(a0_, b1_, acc[0][1], 0, 0, 0); \
    acc[1][0] = __builtin_amdgcn_mfma_f32_16x16x32_bf16(a1_, b0_, acc[1][0], 0, 0, 0); \
    acc[1][1] = __builtin_amdgcn_mfma_f32_16x16x32_bf16(a1_, b1_, acc[1][1], 0, 0, 0); \
    acc[2][0] = __builtin_amdgcn_mfma_f32_16x16x32_bf16(a2_, b0_, acc[2][0], 0, 0, 0); \
    acc[2][1] = __builtin_amdgcn_mfma_f32_16x16x32_bf16(a2_, b1_, acc[2][1], 0, 0, 0); \
    acc[3][0] = __builtin_amdgcn_mfma_f32_16x16x32_bf16(a3_, b0_, acc[3][0], 0, 0, 0); \
    acc[3][1] = __builtin_amdgcn_mfma_f32_16x16x32_bf16(a3_, b1_, acc[3][1], 0, 0, 0); \
  }

    LD(JJ(0), b0A, b1A, a0A, a1A, a2A, a3A);
    int r = 0;
    while (r + 2 <= len - 1) {
      LD(JJ(r + 1), b0B, b1B, a0B, a1B, a2B, a3B);
      FMA(b0A, b1A, a0A, a1A, a2A, a3A);
      LD(JJ(r + 2), b0A, b1A, a0A, a1A, a2A, a3A);
      FMA(b0B, b1B, a0B, a1B, a2B, a3B);
      r += 2;
    }
    if (r < len - 1) {
      LD(JJ(r + 1), b0B, b1B, a0B, a1B, a2B, a3B);
      FMA(b0A, b1A, a0A, a1A, a2A, a3A);
      FMA(b0B, b1B, a0B, a1B, a2B, a3B);
    } else {
      FMA(b0A, b1A, a0A, a1A, a2A, a3A);
    }
#undef JJ
#undef LD
#undef FMA
  }

  // tree reduce: (1->0, 3->2) then (2->0); wave 0 writes out.
  // acc[m][nf][r] -> LDS idx (m*16 + kgrp*4 + r)*32 + nf*16 + row16
  {
    float* b0p = red[0];
    float* b1p = red[1];
    if (wv == 1 || wv == 3) {
      float* b = (wv == 1) ? b0p : b1p;
      #pragma unroll
      for (int m = 0; m < 4; ++m)
        #pragma unroll
        for (int nf = 0; nf < 2; ++nf)
          #pragma unroll
          for (int r = 0; r < 4; ++r)
            b[(m * 16 + kgrp * 4 + r) * 32 + nf * 16 + row16] = acc[m][nf][r];
    }
    __syncthreads();
    if (wv == 0 || wv == 2) {
      const float* b = (wv == 0) ? b0p : b1p;
      #pragma unroll
      for (int m = 0; m < 4; ++m)
        #pragma unroll
        for (int nf = 0; nf < 2; ++nf)
          #pragma unroll
          for (int r = 0; r < 4; ++r)
            acc[m][nf][r] += b[(m * 16 + kgrp * 4 + r) * 32 + nf * 16 + row16];
    }
    __syncthreads();
    if (wv == 2) {
      #pragma unroll
      for (int m = 0; m < 4; ++m)
        #pragma unroll
        for (int nf = 0; nf < 2; ++nf)
          #pragma unroll
          for (int r = 0; r < 4; ++r)
            b0p[(m * 16 + kgrp * 4 + r) * 32 + nf * 16 + row16] = acc[m][nf][r];
    }
    __syncthreads();
    if (wv == 0) {
      #pragma unroll
      for (int m = 0; m < 4; ++m)
        #pragma unroll
        for (int nf = 0; nf < 2; ++nf)
          #pragma unroll
          for (int r = 0; r < 4; ++r) {
            float v = acc[m][nf][r] + b0p[(m * 16 + kgrp * 4 + r) * 32 + nf * 16 + row16];
            const int row = tokBase + m * 16 + kgrp * 4 + r;
            const int col = ob * 32 + nf * 16 + row16;
            y[(size_t)row * 2048 + col] = v;
          }
    }
  }
}

extern "C" void kernel_launch(void* const* d_in, const int* in_sizes, int n_in,
                              void* d_out, int out_size, void* d_ws, size_t ws_size,
                              hipStream_t stream) {
  const float* x  = (const float*)d_in[0];
  const float* w  = (const float*)d_in[1];
  const int*   oi = (const int*)d_in[2];
  const int*   ii = (const int*)d_in[3];
  float* y = (float*)d_out;

  const size_t need = (size_t)(XN8 + WN8) * 16 + 65 * sizeof(int);
  if (ws_size >= need) {
    short8* xb = (short8*)d_ws;
    short8* wb = xb + XN8;
    int* offs = (int*)(wb + WN8);
    cvt_kernel<<<dim3((XN8 + WN8 + 255) / 256), dim3(256), 0, stream>>>(x, w, oi, xb, wb, offs);
    bsl_main<1><<<dim3(2048), dim3(256), 0, stream>>>(xb, wb, offs, x, w, oi, ii, y);
  } else {
    bsl_main<0><<<dim3(2048), dim3(256), 0, stream>>>(nullptr, nullptr, nullptr, x, w, oi, ii, y);
  }
}

// Round 18
// 96.282 us; speedup vs baseline: 2.0537x; 1.0988x over previous
//
#include <hip/hip_runtime.h>

#define N_TOK 2048
#define IN_FEAT 2048
#define NNZB 1228
#define XN8 ((N_TOK * IN_FEAT) / 8)   // x elements / 8
#define WN8 ((NNZB * 1024) / 8)       // w elements / 8

typedef __attribute__((ext_vector_type(8))) short short8;
typedef __attribute__((ext_vector_type(4))) float floatx4;

__device__ __forceinline__ short f2bf(float f) {
  unsigned u = __builtin_bit_cast(unsigned, f);
  u += 0x7FFFu + ((u >> 16) & 1u);   // round-to-nearest-even
  return (short)(u >> 16);
}

__device__ __forceinline__ short8 cvt8(const float4 a, const float4 b) {
  short8 r;
  r[0] = f2bf(a.x); r[1] = f2bf(a.y); r[2] = f2bf(a.z); r[3] = f2bf(a.w);
  r[4] = f2bf(b.x); r[5] = f2bf(b.y); r[6] = f2bf(b.z); r[7] = f2bf(b.w);
  return r;
}

// f32 -> bf16 staging. NEW in this round: xb is written COLUMN-BLOCK-MAJOR:
//   xb[(ib*2048 + token)*32 + col], ib = 32-col block index.
// R17 post-mortem: the old row-major xb put the 16 rows of every MFMA
// A-fragment 4KB apart -> all 16 lines alias ONE L1 set (32KB/64B lines),
// ~119 cy/load-instr vs ~17 expected. Tiled layout makes each A-fragment
// 1KB contiguous (16 distinct sets).
__global__ __launch_bounds__(256) void cvt_kernel(
    const float* __restrict__ x, const float* __restrict__ w,
    const int* __restrict__ oi,
    short8* __restrict__ xb, short8* __restrict__ wb, int* __restrict__ offs) {
  const int tid = blockIdx.x * 256 + threadIdx.x;
  if (blockIdx.x == 0 && threadIdx.x < 65) {
    const int target = threadIdx.x;
    int lo = 0, hi = NNZB;
    while (lo < hi) { int m = (lo + hi) >> 1; if (oi[m] < target) lo = m + 1; else hi = m; }
    offs[threadIdx.x] = lo;
  }
  if (tid < XN8) {
    // output short8 index: ((ib*2048 + tok)*4 + cg), cg in [0,4)
    const int cg  = tid & 3;
    const int tok = (tid >> 2) & (N_TOK - 1);
    const int ib  = tid >> 13;
    const float4* p = (const float4*)x + ((size_t)tok * 512 + ib * 8 + cg * 2);
    xb[tid] = cvt8(p[0], p[1]);
  } else if (tid < XN8 + WN8) {
    const int t = tid - XN8;
    const float4* p = (const float4*)w + (size_t)t * 2;
    wb[t] = cvt8(p[0], p[1]);
  }
}

// wg = 64 tokens x 1 output block; 4 waves split the nnz range (quarters),
// LDS tree-reduce; ii[] preloaded into lanes (readlane index path).
// A-fragment load: xb + ib*8192 + (tokBase+row16)*4 + m*64 + kgrp
//   -> 64 lanes cover 16 consecutive 64B lines = 1KB contiguous.
template <int USE_WS>
__global__ __launch_bounds__(256, 4) void bsl_main(
    const short8* __restrict__ xb, const short8* __restrict__ wb,
    const int* __restrict__ offs,
    const float* __restrict__ x, const float* __restrict__ w,
    const int* __restrict__ oi, const int* __restrict__ ii,
    float* __restrict__ y) {
  const int ob   = blockIdx.x >> 5;
  const int tile = blockIdx.x & 31;
  const int lane = threadIdx.x & 63;
  const int wv   = __builtin_amdgcn_readfirstlane(threadIdx.x >> 6);
  const int row16 = lane & 15;
  const int kgrp  = lane >> 4;   // 0..3

  __shared__ float red[2][64 * 32];

  int e0, e1;
  if (USE_WS) {
    e0 = offs[ob];
    e1 = offs[ob + 1];
  } else {
    int lo = 0, hi = NNZB;
    while (lo < hi) { int m = (lo + hi) >> 1; if (oi[m] < ob) lo = m + 1; else hi = m; }
    e0 = lo;
    hi = NNZB;
    while (lo < hi) { int m = (lo + hi) >> 1; if (oi[m] < ob + 1) lo = m + 1; else hi = m; }
    e1 = lo;
  }
  const int cnt = e1 - e0;

  // preload up to 64 block indices into the wave's lanes (one load total)
  const int safek = (lane < cnt) ? (e0 + lane) : 0;
  const int iiv = ii[safek];

  const int ks = (cnt * wv) >> 2;
  const int ke = (cnt * (wv + 1)) >> 2;

  const int tokBase = tile * 64;

  floatx4 acc[4][2] = {};

  if (USE_WS) {
    // per-lane invariant part of the A address (tiled layout)
    const short8* xbase = xb + (size_t)(tokBase + row16) * 4 + kgrp;
    #pragma unroll 2
    for (int j = ks; j < ke; ++j) {
      const int k = e0 + j;
      const int ib = (j < 64) ? __builtin_amdgcn_readlane(iiv, j) : ii[k];
      const short8* wp = wb + (size_t)k * 128 + row16 * 4 + kgrp;
      short8 b0 = wp[0];
      short8 b1 = wp[64];
      const short8* xp = xbase + (size_t)ib * 8192;
      #pragma unroll
      for (int m = 0; m < 4; ++m) {
        short8 a = xp[m * 64];
        acc[m][0] = __builtin_amdgcn_mfma_f32_16x16x32_bf16(a, b0, acc[m][0], 0, 0, 0);
        acc[m][1] = __builtin_amdgcn_mfma_f32_16x16x32_bf16(a, b1, acc[m][1], 0, 0, 0);
      }
    }
  } else {
    // f32 fallback (workspace too small): row-major x, convert inline
    const float* xrow = x + (size_t)(tokBase + row16) * IN_FEAT + kgrp * 8;
    #pragma unroll 2
    for (int j = ks; j < ke; ++j) {
      const int k = e0 + j;
      const int ib = (j < 64) ? __builtin_amdgcn_readlane(iiv, j) : ii[k];
      const float* wbp = w + (size_t)k * 1024 + kgrp * 8;
      const float4* wp0 = (const float4*)(wbp + row16 * 32);
      const float4* wp1 = (const float4*)(wbp + (row16 + 16) * 32);
      short8 b0 = cvt8(wp0[0], wp0[1]);
      short8 b1 = cvt8(wp1[0], wp1[1]);
      const float* xp = xrow + ib * 32;
      #pragma unroll
      for (int m = 0; m < 4; ++m) {
        const float4* ap = (const float4*)(xp + (size_t)(m * 16) * IN_FEAT);
        short8 a = cvt8(ap[0], ap[1]);
        acc[m][0] = __builtin_amdgcn_mfma_f32_16x16x32_bf16(a, b0, acc[m][0], 0, 0, 0);
        acc[m][1] = __builtin_amdgcn_mfma_f32_16x16x32_bf16(a, b1, acc[m][1], 0, 0, 0);
      }
    }
  }

  // tree reduce: (1->0, 3->2) then (2->0); wave 0 writes out.
  // acc[m][nf][r] -> LDS idx (m*16 + kgrp*4 + r)*32 + nf*16 + row16
  {
    float* b0p = red[0];
    float* b1p = red[1];
    if (wv == 1 || wv == 3) {
      float* b = (wv == 1) ? b0p : b1p;
      #pragma unroll
      for (int m = 0; m < 4; ++m)
        #pragma unroll
        for (int nf = 0; nf < 2; ++nf)
          #pragma unroll
          for (int r = 0; r < 4; ++r)
            b[(m * 16 + kgrp * 4 + r) * 32 + nf * 16 + row16] = acc[m][nf][r];
    }
    __syncthreads();
    if (wv == 0 || wv == 2) {
      const float* b = (wv == 0) ? b0p : b1p;
      #pragma unroll
      for (int m = 0; m < 4; ++m)
        #pragma unroll
        for (int nf = 0; nf < 2; ++nf)
          #pragma unroll
          for (int r = 0; r < 4; ++r)
            acc[m][nf][r] += b[(m * 16 + kgrp * 4 + r) * 32 + nf * 16 + row16];
    }
    __syncthreads();
    if (wv == 2) {
      #pragma unroll
      for (int m = 0; m < 4; ++m)
        #pragma unroll
        for (int nf = 0; nf < 2; ++nf)
          #pragma unroll
          for (int r = 0; r < 4; ++r)
            b0p[(m * 16 + kgrp * 4 + r) * 32 + nf * 16 + row16] = acc[m][nf][r];
    }
    __syncthreads();
    if (wv == 0) {
      #pragma unroll
      for (int m = 0; m < 4; ++m)
        #pragma unroll
        for (int nf = 0; nf < 2; ++nf)
          #pragma unroll
          for (int r = 0; r < 4; ++r) {
            float v = acc[m][nf][r] + b0p[(m * 16 + kgrp * 4 + r) * 32 + nf * 16 + row16];
            const int row = tokBase + m * 16 + kgrp * 4 + r;
            const int col = ob * 32 + nf * 16 + row16;
            y[(size_t)row * 2048 + col] = v;
          }
    }
  }
}

extern "C" void kernel_launch(void* const* d_in, const int* in_sizes, int n_in,
                              void* d_out, int out_size, void* d_ws, size_t ws_size,
                              hipStream_t stream) {
  const float* x  = (const float*)d_in[0];
  const float* w  = (const float*)d_in[1];
  const int*   oi = (const int*)d_in[2];
  const int*   ii = (const int*)d_in[3];
  float* y = (float*)d_out;

  const size_t need = (size_t)(XN8 + WN8) * 16 + 65 * sizeof(int);
  if (ws_size >= need) {
    short8* xb = (short8*)d_ws;
    short8* wb = xb + XN8;
    int* offs = (int*)(wb + WN8);
    cvt_kernel<<<dim3((XN8 + WN8 + 255) / 256), dim3(256), 0, stream>>>(x, w, oi, xb, wb, offs);
    bsl_main<1><<<dim3(2048), dim3(256), 0, stream>>>(xb, wb, offs, x, w, oi, ii, y);
  } else {
    bsl_main<0><<<dim3(2048), dim3(256), 0, stream>>>(nullptr, nullptr, nullptr, x, w, oi, ii, y);
  }
}